// Round 1
// baseline (252.566 us; speedup 1.0000x reference)
//
#include <hip/hip_runtime.h>
#include <hip/hip_bf16.h>

#define HID 64
#define NGr 16
#define NPG 160
#define NN  2560            // NGr*NPG
#define EE  40960
#define PPG 25600           // NPG*NPG
#define PT  409600          // NGr*PPG
#define AV  64
#define BV  8
#define EPSB 1e-5f

// ---------------- prep: combined weights + zero stats ----------------
// W1c = W1 @ L0w[0:64]; b1c = b1 @ L0w[0:64] + L0_b
// W2c = W2 @ L0w[64:128]; b2c = b2 @ L0w[64:128]
// Wec = We @ L0w[128:192]; bec = be @ L0w[128:192]
__global__ void k_prep(const float* __restrict__ W1, const float* __restrict__ b1,
                       const float* __restrict__ W2, const float* __restrict__ b2,
                       const float* __restrict__ We, const float* __restrict__ be,
                       const float* __restrict__ L0w, const float* __restrict__ L0b,
                       float* __restrict__ W1c, float* __restrict__ W2c, float* __restrict__ Wec,
                       float* __restrict__ b1c, float* __restrict__ b2c, float* __restrict__ bec,
                       float* __restrict__ stats) {
    int blk = blockIdx.x, tid = threadIdx.x;
    if (blk == 3) { stats[tid] = 0.f; return; }   // 256 threads zero 256 stat floats
    const float* Wsrc = (blk == 0) ? W1 : (blk == 1) ? W2 : We;
    const float* bsrc = (blk == 0) ? b1 : (blk == 1) ? b2 : be;
    const float* L    = L0w + blk * 64 * 64;
    float* Wdst = (blk == 0) ? W1c : (blk == 1) ? W2c : Wec;
    float* bdst = (blk == 0) ? b1c : (blk == 1) ? b2c : bec;
    for (int idx = tid; idx < 4096; idx += 256) {
        int k = idx >> 6, h = idx & 63;
        float acc = 0.f;
        for (int m = 0; m < 64; ++m) acc = fmaf(Wsrc[k * 64 + m], L[m * 64 + h], acc);
        Wdst[idx] = acc;
    }
    if (tid < 64) {
        int h = tid;
        float acc = (blk == 0) ? L0b[h] : 0.f;
        for (int m = 0; m < 64; ++m) acc = fmaf(bsrc[m], L[m * 64 + h], acc);
        bdst[h] = acc;
    }
}

// ---------------- nodes: x_emb -> A, B (2560 x 64 each) ----------------
__global__ void k_nodes(const float* __restrict__ atab, const int* __restrict__ x,
                        const float* __restrict__ W1c, const float* __restrict__ W2c,
                        const float* __restrict__ b1c, const float* __restrict__ b2c,
                        float* __restrict__ A, float* __restrict__ Bm) {
    int n = blockIdx.x, h = threadIdx.x;
    __shared__ float xe[64];
    float v = 0.f;
#pragma unroll
    for (int c = 0; c < 9; ++c) v += atab[c * AV * HID + x[n * 9 + c] * HID + h];
    xe[h] = v;
    __syncthreads();
    float a = b1c[h], b = b2c[h];
#pragma unroll
    for (int k = 0; k < 64; ++k) {
        float xk = xe[k];
        a = fmaf(xk, W1c[k * 64 + h], a);
        b = fmaf(xk, W2c[k * 64 + h], b);
    }
    A[n * 64 + h] = a;
    Bm[n * 64 + h] = b;
}

// ---------------- dense fill: z0 = A[i] + B[j], fused BN0 stats ----------------
__global__ void __launch_bounds__(256) k_dense(const float* __restrict__ A, const float* __restrict__ Bm,
                                               float* __restrict__ zbuf, float* __restrict__ stats) {
    int h = threadIdx.x & 63;
    int wid = threadIdx.x >> 6;
    int wavesTotal = gridDim.x * 4;
    int wave = blockIdx.x * 4 + wid;
    float s = 0.f, ss = 0.f;
    for (int row = wave; row < PT; row += wavesTotal) {
        int g = row / PPG;
        int rem = row - g * PPG;
        int i = rem / NPG;
        int j = rem - i * NPG;
        float v = A[(g * NPG + i) * 64 + h] + Bm[(g * NPG + j) * 64 + h];
        zbuf[(size_t)row * 64 + h] = v;
        s += v;
        ss = fmaf(v, v, ss);
    }
    __shared__ float ls[128];
    if (threadIdx.x < 128) ls[threadIdx.x] = 0.f;
    __syncthreads();
    atomicAdd(&ls[h], s);
    atomicAdd(&ls[64 + h], ss);
    __syncthreads();
    if (threadIdx.x < 128) atomicAdd(&stats[threadIdx.x], ls[threadIdx.x]);
}

// ---------------- edges: Ew = (bond_emb @ Wec + bec); scatter into z0; exact stats fix ----------------
__global__ void __launch_bounds__(256) k_edges(const float* __restrict__ btab, const int* __restrict__ eattr,
                                               const int* __restrict__ epos,
                                               const float* __restrict__ Wec, const float* __restrict__ bec,
                                               float* __restrict__ zbuf, float* __restrict__ stats) {
    int h = threadIdx.x & 63;
    int el = threadIdx.x >> 6;          // wave id = edge slot
    __shared__ float ea[4][64];
    float s = 0.f, ss = 0.f;
    for (int base = blockIdx.x * 4; base < EE; base += gridDim.x * 4) {
        int e = base + el;
        float v = 0.f;
#pragma unroll
        for (int c = 0; c < 3; ++c) v += btab[c * BV * HID + eattr[e * 3 + c] * HID + h];
        ea[el][h] = v;
        __syncthreads();
        float ew = bec[h];
#pragma unroll
        for (int k = 0; k < 64; ++k) ew = fmaf(ea[el][k], Wec[k * 64 + h], ew);
        int p = epos[e];
        float old = atomicAdd(&zbuf[(size_t)p * 64 + h], ew);
        s += ew;
        ss += 2.f * old * ew + ew * ew;   // (old+ew)^2 - old^2, exact under any atomic order
        __syncthreads();
    }
    __shared__ float ls[128];
    if (threadIdx.x < 128) ls[threadIdx.x] = 0.f;
    __syncthreads();
    atomicAdd(&ls[h], s);
    atomicAdd(&ls[64 + h], ss);
    __syncthreads();
    if (threadIdx.x < 128) atomicAdd(&stats[threadIdx.x], ls[threadIdx.x]);
}

// ---------------- mid: h0 = relu(BN0(z0)); z1 = h0 @ L1 + b1 (in place); BN1 stats ----------------
__global__ void __launch_bounds__(256) k_mid(const float* __restrict__ L1w, const float* __restrict__ L1b,
                                             const float* __restrict__ g0, const float* __restrict__ beta0,
                                             float* __restrict__ zbuf, float* __restrict__ stats) {
    int h = threadIdx.x & 63;
    int wid = threadIdx.x >> 6;
    const float invP = 1.f / (float)PT;
    float mu = stats[h] * invP;
    float var = stats[64 + h] * invP - mu * mu;
    float inv = rsqrtf(var + EPSB);
    float s0 = g0[h] * inv;
    float t0 = fmaf(-mu, s0, beta0[h]);
    float w[64];
#pragma unroll
    for (int k = 0; k < 64; ++k) w[k] = L1w[k * 64 + h];
    float bias = L1b[h];
    int wavesTotal = gridDim.x * 4;
    int stride = wavesTotal;
    int row = blockIdx.x * 4 + wid;
    float s = 0.f, ss = 0.f;
    if (row < PT) {
        float z = zbuf[(size_t)row * 64 + h];
        while (true) {
            int nrow = row + stride;
            float znext = (nrow < PT) ? zbuf[(size_t)nrow * 64 + h] : 0.f;  // prefetch
            float h0 = fmaxf(fmaf(z, s0, t0), 0.f);
            int h0b = __float_as_int(h0);
            float a0 = bias, a1 = 0.f, a2 = 0.f, a3 = 0.f;
#pragma unroll
            for (int k = 0; k < 64; k += 4) {
                a0 = fmaf(__int_as_float(__builtin_amdgcn_readlane(h0b, k)),     w[k],     a0);
                a1 = fmaf(__int_as_float(__builtin_amdgcn_readlane(h0b, k + 1)), w[k + 1], a1);
                a2 = fmaf(__int_as_float(__builtin_amdgcn_readlane(h0b, k + 2)), w[k + 2], a2);
                a3 = fmaf(__int_as_float(__builtin_amdgcn_readlane(h0b, k + 3)), w[k + 3], a3);
            }
            float z1 = (a0 + a1) + (a2 + a3);
            zbuf[(size_t)row * 64 + h] = z1;
            s += z1;
            ss = fmaf(z1, z1, ss);
            if (nrow >= PT) break;
            row = nrow;
            z = znext;
        }
    }
    __shared__ float ls[128];
    if (threadIdx.x < 128) ls[threadIdx.x] = 0.f;
    __syncthreads();
    atomicAdd(&ls[h], s);
    atomicAdd(&ls[64 + h], ss);
    __syncthreads();
    if (threadIdx.x < 128) atomicAdd(&stats[128 + threadIdx.x], ls[threadIdx.x]);
}

// ---------------- final: out = relu(BN1(z1)) . L2w + L2b ----------------
__global__ void __launch_bounds__(256) k_final(const float* __restrict__ g1, const float* __restrict__ beta1,
                                               const float* __restrict__ L2w, const float* __restrict__ L2b,
                                               const float* __restrict__ zbuf, float* __restrict__ out,
                                               const float* __restrict__ stats) {
    int lane = threadIdx.x & 63;
    int wid = threadIdx.x >> 6;
    int q = lane & 15;     // quad within row
    int rl = lane >> 4;    // row within group of 4
    const float invP = 1.f / (float)PT;
    float s1[4], t1[4], wv[4];
#pragma unroll
    for (int c = 0; c < 4; ++c) {
        int col = q * 4 + c;
        float mu = stats[128 + col] * invP;
        float var = stats[192 + col] * invP - mu * mu;
        float inv = rsqrtf(var + EPSB);
        s1[c] = g1[col] * inv;
        t1[c] = fmaf(-mu, s1[c], beta1[col]);
        wv[c] = L2w[col];
    }
    float bias = L2b[0];
    int waveId = blockIdx.x * 4 + wid;
    int stride = gridDim.x * 16;
    for (int base = waveId * 4; base < PT; base += stride) {
        const float4 zv = *reinterpret_cast<const float4*>(zbuf + (size_t)base * 64 + lane * 4);
        float p;
        p  = fmaxf(fmaf(zv.x, s1[0], t1[0]), 0.f) * wv[0];
        p  = fmaf(fmaxf(fmaf(zv.y, s1[1], t1[1]), 0.f), wv[1], p);
        p  = fmaf(fmaxf(fmaf(zv.z, s1[2], t1[2]), 0.f), wv[2], p);
        p  = fmaf(fmaxf(fmaf(zv.w, s1[3], t1[3]), 0.f), wv[3], p);
        p += __shfl_xor(p, 1);
        p += __shfl_xor(p, 2);
        p += __shfl_xor(p, 4);
        p += __shfl_xor(p, 8);
        if (q == 0) out[base + rl] = p + bias;
    }
}

extern "C" void kernel_launch(void* const* d_in, const int* in_sizes, int n_in,
                              void* d_out, int out_size, void* d_ws, size_t ws_size,
                              hipStream_t stream) {
    const float* atab  = (const float*)d_in[0];
    const float* btab  = (const float*)d_in[1];
    const float* W1    = (const float*)d_in[2];
    const float* b1    = (const float*)d_in[3];
    const float* W2    = (const float*)d_in[4];
    const float* b2    = (const float*)d_in[5];
    const float* We    = (const float*)d_in[6];
    const float* be    = (const float*)d_in[7];
    const float* L0w   = (const float*)d_in[8];
    const float* L0b   = (const float*)d_in[9];
    const float* L1w   = (const float*)d_in[10];
    const float* L1b   = (const float*)d_in[11];
    const float* L2w   = (const float*)d_in[12];
    const float* L2b   = (const float*)d_in[13];
    const float* g0    = (const float*)d_in[14];
    const float* beta0 = (const float*)d_in[15];
    const float* g1    = (const float*)d_in[16];
    const float* beta1 = (const float*)d_in[17];
    const int*   x     = (const int*)d_in[18];
    const int*   eattr = (const int*)d_in[19];
    // d_in[20], d_in[21] = idx0, idx1 (structured; computed arithmetically)
    const int*   epos  = (const int*)d_in[22];
    float* out = (float*)d_out;

    // workspace layout (floats)
    float* ws = (float*)d_ws;
    float* zbuf = ws;                       // PT*64 = 26,214,400
    float* A    = zbuf + (size_t)PT * 64;   // 163,840
    float* Bm   = A + NN * 64;              // 163,840
    float* W1c  = Bm + NN * 64;             // 4096
    float* W2c  = W1c + 4096;               // 4096
    float* Wec  = W2c + 4096;               // 4096
    float* b1c  = Wec + 4096;               // 64
    float* b2c  = b1c + 64;                 // 64
    float* bec  = b2c + 64;                 // 64
    float* stats = bec + 64;                // 256: sum0,ss0,sum1,ss1

    k_prep<<<4, 256, 0, stream>>>(W1, b1, W2, b2, We, be, L0w, L0b,
                                  W1c, W2c, Wec, b1c, b2c, bec, stats);
    k_nodes<<<NN, 64, 0, stream>>>(atab, x, W1c, W2c, b1c, b2c, A, Bm);
    k_dense<<<2048, 256, 0, stream>>>(A, Bm, zbuf, stats);
    k_edges<<<512, 256, 0, stream>>>(btab, eattr, epos, Wec, bec, zbuf, stats);
    k_mid<<<2048, 256, 0, stream>>>(L1w, L1b, g0, beta0, zbuf, stats);
    k_final<<<1024, 256, 0, stream>>>(g1, beta1, L2w, L2b, zbuf, out, stats);
}

// Round 2
// 231.418 us; speedup vs baseline: 1.0914x; 1.0914x over previous
//
#include <hip/hip_runtime.h>
#include <hip/hip_bf16.h>

#define HID 64
#define NGr 16
#define NPG 160
#define NN  2560            // NGr*NPG
#define EE  40960
#define PPG 25600           // NPG*NPG
#define PT  409600          // NGr*PPG
#define AV  64
#define BV  8
#define EPSB 1e-5f

typedef __attribute__((ext_vector_type(8))) short short8v;   // 8 bf16 (4 VGPRs)
typedef __attribute__((ext_vector_type(4))) float f32x4;

static __device__ __forceinline__ unsigned short bf16_hi(float v) {
    return (unsigned short)(__float_as_uint(v) >> 16);
}
static __device__ __forceinline__ float bf16_val(unsigned short h) {
    return __uint_as_float(((unsigned int)h) << 16);
}

// ---------------- prep: combined weights + zero stats + bf16-split L1w ----------------
__global__ void k_prep(const float* __restrict__ W1, const float* __restrict__ b1,
                       const float* __restrict__ W2, const float* __restrict__ b2,
                       const float* __restrict__ We, const float* __restrict__ be,
                       const float* __restrict__ L0w, const float* __restrict__ L0b,
                       const float* __restrict__ L1w,
                       float* __restrict__ W1c, float* __restrict__ W2c, float* __restrict__ Wec,
                       float* __restrict__ b1c, float* __restrict__ b2c, float* __restrict__ bec,
                       float* __restrict__ stats,
                       unsigned short* __restrict__ WBhi, unsigned short* __restrict__ WBlo) {
    int blk = blockIdx.x, tid = threadIdx.x;
    if (blk == 3) {
        stats[tid] = 0.f;                 // 256 threads zero 256 stat floats
        for (int idx = tid; idx < 4096; idx += 256) {
            float w = L1w[idx];
            unsigned short hi = bf16_hi(w);
            float rem = w - bf16_val(hi);
            WBhi[idx] = hi;
            WBlo[idx] = bf16_hi(rem);
        }
        return;
    }
    const float* Wsrc = (blk == 0) ? W1 : (blk == 1) ? W2 : We;
    const float* bsrc = (blk == 0) ? b1 : (blk == 1) ? b2 : be;
    const float* L    = L0w + blk * 64 * 64;
    float* Wdst = (blk == 0) ? W1c : (blk == 1) ? W2c : Wec;
    float* bdst = (blk == 0) ? b1c : (blk == 1) ? b2c : bec;
    for (int idx = tid; idx < 4096; idx += 256) {
        int k = idx >> 6, h = idx & 63;
        float acc = 0.f;
        for (int m = 0; m < 64; ++m) acc = fmaf(Wsrc[k * 64 + m], L[m * 64 + h], acc);
        Wdst[idx] = acc;
    }
    if (tid < 64) {
        int h = tid;
        float acc = (blk == 0) ? L0b[h] : 0.f;
        for (int m = 0; m < 64; ++m) acc = fmaf(bsrc[m], L[m * 64 + h], acc);
        bdst[h] = acc;
    }
}

// ---------------- nodes: x_emb -> A, B (2560 x 64 each) ----------------
__global__ void k_nodes(const float* __restrict__ atab, const int* __restrict__ x,
                        const float* __restrict__ W1c, const float* __restrict__ W2c,
                        const float* __restrict__ b1c, const float* __restrict__ b2c,
                        float* __restrict__ A, float* __restrict__ Bm) {
    int n = blockIdx.x, h = threadIdx.x;
    __shared__ float xe[64];
    float v = 0.f;
#pragma unroll
    for (int c = 0; c < 9; ++c) v += atab[c * AV * HID + x[n * 9 + c] * HID + h];
    xe[h] = v;
    __syncthreads();
    float a = b1c[h], b = b2c[h];
#pragma unroll
    for (int k = 0; k < 64; ++k) {
        float xk = xe[k];
        a = fmaf(xk, W1c[k * 64 + h], a);
        b = fmaf(xk, W2c[k * 64 + h], b);
    }
    A[n * 64 + h] = a;
    Bm[n * 64 + h] = b;
}

// ---------------- dense fill: z0 = A[i] + B[j], fused BN0 stats ----------------
__global__ void __launch_bounds__(256) k_dense(const float* __restrict__ A, const float* __restrict__ Bm,
                                               float* __restrict__ zbuf, float* __restrict__ stats) {
    int h = threadIdx.x & 63;
    int wid = threadIdx.x >> 6;
    int wavesTotal = gridDim.x * 4;
    int wave = blockIdx.x * 4 + wid;
    float s = 0.f, ss = 0.f;
    for (int row = wave; row < PT; row += wavesTotal) {
        int g = row / PPG;
        int rem = row - g * PPG;
        int i = rem / NPG;
        int j = rem - i * NPG;
        float v = A[(g * NPG + i) * 64 + h] + Bm[(g * NPG + j) * 64 + h];
        zbuf[(size_t)row * 64 + h] = v;
        s += v;
        ss = fmaf(v, v, ss);
    }
    __shared__ float ls[128];
    if (threadIdx.x < 128) ls[threadIdx.x] = 0.f;
    __syncthreads();
    atomicAdd(&ls[h], s);
    atomicAdd(&ls[64 + h], ss);
    __syncthreads();
    if (threadIdx.x < 128) atomicAdd(&stats[threadIdx.x], ls[threadIdx.x]);
}

// ---------------- edges: Ew = (bond_emb @ Wec + bec); scatter into z0; exact stats fix ----------------
__global__ void __launch_bounds__(256) k_edges(const float* __restrict__ btab, const int* __restrict__ eattr,
                                               const int* __restrict__ epos,
                                               const float* __restrict__ Wec, const float* __restrict__ bec,
                                               float* __restrict__ zbuf, float* __restrict__ stats) {
    int h = threadIdx.x & 63;
    int el = threadIdx.x >> 6;          // wave id = edge slot
    __shared__ float ea[4][64];
    float s = 0.f, ss = 0.f;
    for (int base = blockIdx.x * 4; base < EE; base += gridDim.x * 4) {
        int e = base + el;
        float v = 0.f;
#pragma unroll
        for (int c = 0; c < 3; ++c) v += btab[c * BV * HID + eattr[e * 3 + c] * HID + h];
        ea[el][h] = v;
        __syncthreads();
        float ew = bec[h];
#pragma unroll
        for (int k = 0; k < 64; ++k) ew = fmaf(ea[el][k], Wec[k * 64 + h], ew);
        int p = epos[e];
        float old = atomicAdd(&zbuf[(size_t)p * 64 + h], ew);
        s += ew;
        ss += 2.f * old * ew + ew * ew;   // (old+ew)^2 - old^2, exact under any atomic order
        __syncthreads();
    }
    __shared__ float ls[128];
    if (threadIdx.x < 128) ls[threadIdx.x] = 0.f;
    __syncthreads();
    atomicAdd(&ls[h], s);
    atomicAdd(&ls[64 + h], ss);
    __syncthreads();
    if (threadIdx.x < 128) atomicAdd(&stats[threadIdx.x], ls[threadIdx.x]);
}

// ---------------- mid (MFMA): h0 = relu(BN0(z0)); z1 = h0 @ L1 + b1 (in place); BN1 stats ----------------
// bf16 hi/lo split: z1 = hHi@wHi + hHi@wLo + hLo@wHi  (err ~2^-17 rel)
// A-frag: lane l -> row (l&15), k = (l>>4)*8 + j  (j=0..7), per K-step of 32
// B-frag: lane l -> k = (l>>4)*8 + j, col (l&15)
// D:      lane l -> col (l&15), row (l>>4)*4 + reg
__global__ void __launch_bounds__(256) k_mid(const unsigned short* __restrict__ WBhi,
                                             const unsigned short* __restrict__ WBlo,
                                             const float* __restrict__ L1b,
                                             const float* __restrict__ g0, const float* __restrict__ beta0,
                                             float* __restrict__ zbuf, float* __restrict__ stats) {
    int lane = threadIdx.x & 63;
    int wid  = blockIdx.x * 4 + (threadIdx.x >> 6);
    int nWaves = gridDim.x * 4;
    int r16 = lane & 15;
    int kg  = lane >> 4;

    const float invP = 1.f / (float)PT;
    // BN0 coeffs for this lane's k-columns (two K-halves)
    float s0a[8], t0a[8], s0b[8], t0b[8];
#pragma unroll
    for (int j = 0; j < 8; ++j) {
        int k = kg * 8 + j;
        float mu = stats[k] * invP;
        float var = stats[64 + k] * invP - mu * mu;
        float inv = rsqrtf(var + EPSB);
        s0a[j] = g0[k] * inv;
        t0a[j] = fmaf(-mu, s0a[j], beta0[k]);
        int k2 = k + 32;
        float mu2 = stats[k2] * invP;
        float var2 = stats[64 + k2] * invP - mu2 * mu2;
        float inv2 = rsqrtf(var2 + EPSB);
        s0b[j] = g0[k2] * inv2;
        t0b[j] = fmaf(-mu2, s0b[j], beta0[k2]);
    }
    // B fragments (weights), loaded once per wave: [col-tile][K-step]
    short8v Bhi[4][2], Blo[4][2];
#pragma unroll
    for (int ct = 0; ct < 4; ++ct)
#pragma unroll
        for (int ks = 0; ks < 2; ++ks)
#pragma unroll
            for (int j = 0; j < 8; ++j) {
                int k = ks * 32 + kg * 8 + j;
                int idx = k * 64 + ct * 16 + r16;
                Bhi[ct][ks][j] = (short)WBhi[idx];
                Blo[ct][ks][j] = (short)WBlo[idx];
            }
    float biasv[4];
#pragma unroll
    for (int ct = 0; ct < 4; ++ct) biasv[ct] = L1b[ct * 16 + r16];

    float sum[4] = {0.f, 0.f, 0.f, 0.f}, ssum[4] = {0.f, 0.f, 0.f, 0.f};

    for (int tile = wid; tile < PT / 16; tile += nWaves) {
        float* tb = zbuf + (size_t)tile * 16 * 64;
        const float4 za0 = *reinterpret_cast<const float4*>(tb + r16 * 64 + kg * 8);
        const float4 za1 = *reinterpret_cast<const float4*>(tb + r16 * 64 + kg * 8 + 4);
        const float4 zb0 = *reinterpret_cast<const float4*>(tb + r16 * 64 + 32 + kg * 8);
        const float4 zb1 = *reinterpret_cast<const float4*>(tb + r16 * 64 + 32 + kg * 8 + 4);
        float ha[8] = {za0.x, za0.y, za0.z, za0.w, za1.x, za1.y, za1.z, za1.w};
        float hb[8] = {zb0.x, zb0.y, zb0.z, zb0.w, zb1.x, zb1.y, zb1.z, zb1.w};
        short8v aHi0, aLo0, aHi1, aLo1;
#pragma unroll
        for (int j = 0; j < 8; ++j) {
            float hv = fmaxf(fmaf(ha[j], s0a[j], t0a[j]), 0.f);
            unsigned short hi = bf16_hi(hv);
            float rem = hv - bf16_val(hi);
            aHi0[j] = (short)hi;
            aLo0[j] = (short)bf16_hi(rem);
            float hv2 = fmaxf(fmaf(hb[j], s0b[j], t0b[j]), 0.f);
            unsigned short hi2 = bf16_hi(hv2);
            float rem2 = hv2 - bf16_val(hi2);
            aHi1[j] = (short)hi2;
            aLo1[j] = (short)bf16_hi(rem2);
        }
        f32x4 acc[4];
#pragma unroll
        for (int ct = 0; ct < 4; ++ct) acc[ct] = (f32x4){0.f, 0.f, 0.f, 0.f};
#pragma unroll
        for (int ct = 0; ct < 4; ++ct) {
            acc[ct] = __builtin_amdgcn_mfma_f32_16x16x32_bf16(aHi0, Bhi[ct][0], acc[ct], 0, 0, 0);
            acc[ct] = __builtin_amdgcn_mfma_f32_16x16x32_bf16(aHi0, Blo[ct][0], acc[ct], 0, 0, 0);
            acc[ct] = __builtin_amdgcn_mfma_f32_16x16x32_bf16(aLo0, Bhi[ct][0], acc[ct], 0, 0, 0);
            acc[ct] = __builtin_amdgcn_mfma_f32_16x16x32_bf16(aHi1, Bhi[ct][1], acc[ct], 0, 0, 0);
            acc[ct] = __builtin_amdgcn_mfma_f32_16x16x32_bf16(aHi1, Blo[ct][1], acc[ct], 0, 0, 0);
            acc[ct] = __builtin_amdgcn_mfma_f32_16x16x32_bf16(aLo1, Bhi[ct][1], acc[ct], 0, 0, 0);
        }
        // epilogue: D lane -> col r16, row kg*4+reg
#pragma unroll
        for (int ct = 0; ct < 4; ++ct) {
#pragma unroll
            for (int reg = 0; reg < 4; ++reg) {
                float z = acc[ct][reg] + biasv[ct];
                tb[(kg * 4 + reg) * 64 + ct * 16 + r16] = z;
                sum[ct] += z;
                ssum[ct] = fmaf(z, z, ssum[ct]);
            }
        }
    }
    // reduce stats across lanes sharing a column (xor 16, 32), then atomics from kg==0
#pragma unroll
    for (int ct = 0; ct < 4; ++ct) {
        float s = sum[ct];
        s += __shfl_xor(s, 16);
        s += __shfl_xor(s, 32);
        float q = ssum[ct];
        q += __shfl_xor(q, 16);
        q += __shfl_xor(q, 32);
        if (kg == 0) {
            atomicAdd(&stats[128 + ct * 16 + r16], s);
            atomicAdd(&stats[192 + ct * 16 + r16], q);
        }
    }
}

// ---------------- final: out = relu(BN1(z1)) . L2w + L2b ----------------
__global__ void __launch_bounds__(256) k_final(const float* __restrict__ g1, const float* __restrict__ beta1,
                                               const float* __restrict__ L2w, const float* __restrict__ L2b,
                                               const float* __restrict__ zbuf, float* __restrict__ out,
                                               const float* __restrict__ stats) {
    int lane = threadIdx.x & 63;
    int wid = threadIdx.x >> 6;
    int q = lane & 15;     // quad within row
    int rl = lane >> 4;    // row within group of 4
    const float invP = 1.f / (float)PT;
    float s1[4], t1[4], wv[4];
#pragma unroll
    for (int c = 0; c < 4; ++c) {
        int col = q * 4 + c;
        float mu = stats[128 + col] * invP;
        float var = stats[192 + col] * invP - mu * mu;
        float inv = rsqrtf(var + EPSB);
        s1[c] = g1[col] * inv;
        t1[c] = fmaf(-mu, s1[c], beta1[col]);
        wv[c] = L2w[col];
    }
    float bias = L2b[0];
    int waveId = blockIdx.x * 4 + wid;
    int stride = gridDim.x * 16;
    for (int base = waveId * 4; base < PT; base += stride) {
        const float4 zv = *reinterpret_cast<const float4*>(zbuf + (size_t)base * 64 + lane * 4);
        float p;
        p  = fmaxf(fmaf(zv.x, s1[0], t1[0]), 0.f) * wv[0];
        p  = fmaf(fmaxf(fmaf(zv.y, s1[1], t1[1]), 0.f), wv[1], p);
        p  = fmaf(fmaxf(fmaf(zv.z, s1[2], t1[2]), 0.f), wv[2], p);
        p  = fmaf(fmaxf(fmaf(zv.w, s1[3], t1[3]), 0.f), wv[3], p);
        p += __shfl_xor(p, 1);
        p += __shfl_xor(p, 2);
        p += __shfl_xor(p, 4);
        p += __shfl_xor(p, 8);
        if (q == 0) out[base + rl] = p + bias;
    }
}

extern "C" void kernel_launch(void* const* d_in, const int* in_sizes, int n_in,
                              void* d_out, int out_size, void* d_ws, size_t ws_size,
                              hipStream_t stream) {
    const float* atab  = (const float*)d_in[0];
    const float* btab  = (const float*)d_in[1];
    const float* W1    = (const float*)d_in[2];
    const float* b1    = (const float*)d_in[3];
    const float* W2    = (const float*)d_in[4];
    const float* b2    = (const float*)d_in[5];
    const float* We    = (const float*)d_in[6];
    const float* be    = (const float*)d_in[7];
    const float* L0w   = (const float*)d_in[8];
    const float* L0b   = (const float*)d_in[9];
    const float* L1w   = (const float*)d_in[10];
    const float* L1b   = (const float*)d_in[11];
    const float* L2w   = (const float*)d_in[12];
    const float* L2b   = (const float*)d_in[13];
    const float* g0    = (const float*)d_in[14];
    const float* beta0 = (const float*)d_in[15];
    const float* g1    = (const float*)d_in[16];
    const float* beta1 = (const float*)d_in[17];
    const int*   x     = (const int*)d_in[18];
    const int*   eattr = (const int*)d_in[19];
    // d_in[20], d_in[21] = idx0, idx1 (structured; computed arithmetically)
    const int*   epos  = (const int*)d_in[22];
    float* out = (float*)d_out;

    // workspace layout (floats)
    float* ws = (float*)d_ws;
    float* zbuf = ws;                       // PT*64 = 26,214,400
    float* A    = zbuf + (size_t)PT * 64;   // 163,840
    float* Bm   = A + NN * 64;              // 163,840
    float* W1c  = Bm + NN * 64;             // 4096
    float* W2c  = W1c + 4096;               // 4096
    float* Wec  = W2c + 4096;               // 4096
    float* b1c  = Wec + 4096;               // 64
    float* b2c  = b1c + 64;                 // 64
    float* bec  = b2c + 64;                 // 64
    float* stats = bec + 64;                // 256: sum0,ss0,sum1,ss1
    unsigned short* WBhi = (unsigned short*)(stats + 256);  // 4096 ushort
    unsigned short* WBlo = WBhi + 4096;                     // 4096 ushort

    k_prep<<<4, 256, 0, stream>>>(W1, b1, W2, b2, We, be, L0w, L0b, L1w,
                                  W1c, W2c, Wec, b1c, b2c, bec, stats, WBhi, WBlo);
    k_nodes<<<NN, 64, 0, stream>>>(atab, x, W1c, W2c, b1c, b2c, A, Bm);
    k_dense<<<2048, 256, 0, stream>>>(A, Bm, zbuf, stats);
    k_edges<<<512, 256, 0, stream>>>(btab, eattr, epos, Wec, bec, zbuf, stats);
    k_mid<<<512, 256, 0, stream>>>(WBhi, WBlo, L1b, g0, beta0, zbuf, stats);
    k_final<<<1024, 256, 0, stream>>>(g1, beta1, L2w, L2b, zbuf, out, stats);
}